// Round 4
// baseline (425.823 us; speedup 1.0000x reference)
//
#include <hip/hip_runtime.h>
#include <cmath>

// ---------------------------------------------------------------------------
// WireframeDetector: NMS -> top-k 300 junctions -> line sampling (bilinear +
// maxpool) -> 3-layer MLP (fp16 MFMA for the two 1024-wide GEMMs).
// R19: R18 + __launch_bounds__(256, 3) on the GEMM (was 2). Makespan model
//      (validated on R18: 3 blocks/worst-CU x 0.77 MB / 27 GB/s = 85.5 us ==
//      measured): no bandwidth is saturated (HBM 15%, L2 ~4/34.5 TB/s) ->
//      the 27 GB/s/CU delivery is a latency/serialization wall of the
//      {issue G2L -> vmcnt(0) -> barrier} round. Cross-BLOCK interleave is
//      what hides it (R18's 2 blocks/CU beat R16/17's 1 block/CU 8-wave);
//      3 co-resident blocks/CU (LDS 48KiBx3=144<=160, VGPR 100<=170) should
//      raise delivered GB/s/CU. Numerically bit-identical to R18.
// ---------------------------------------------------------------------------

typedef _Float16 f16;
typedef _Float16 f16x2 __attribute__((ext_vector_type(2)));
typedef _Float16 f16x8 __attribute__((ext_vector_type(8)));
typedef float f32x4 __attribute__((ext_vector_type(4)));

#define HWD 128
#define NPIX 16384            // 128*128
#define TOPK_N 300
#define NLINES 20000
#define MPAD 20096            // 157 * 128
#define KDIM 1024
#define NDIM 1024
#define MAXCAND 4096

// async global->LDS, 16B per lane; LDS dest = wave-uniform base + lane*16
#define G2L(gp, lp) __builtin_amdgcn_global_load_lds( \
    (const __attribute__((address_space(1))) void*)(gp), \
    (__attribute__((address_space(3))) void*)(lp), 16, 0, 0)

// ---------------------------------------------------------------------------
// Fused preprocessing, one dispatch of 764 blocks:
//   blocks 0..127   : transpose loi [C][H][W] fp32 -> loiT [H][W][C] fp16
//   blocks 128..639 : W1/W2 [K][N] fp32 -> K-chunk-tiled fp16
//                     Wt[((k>>5)*1024 + n)*32 + (k&31)]
//   blocks 640..703 : 3x3 NMS on jloc, survivors -> cand list
//   blocks 704..763 : zero out[60000] (consumed by gemm2's atomicAdd epilogue)
// ---------------------------------------------------------------------------
__global__ __launch_bounds__(256) void preproc_kernel(
    const float* __restrict__ loi, f16* __restrict__ loiT,
    const float* __restrict__ W1, f16* __restrict__ W1T,
    const float* __restrict__ W2, f16* __restrict__ W2T,
    const float* __restrict__ jloc, unsigned long long* __restrict__ cand,
    int* __restrict__ count, float* __restrict__ out, int out_n)
{
    const int bid = blockIdx.x;
    const int tid = threadIdx.x;
    if (bid < 128) {
        __shared__ f16 t[128 * 130];     // [x][c], +2 pad kills bank conflicts
        const int y = bid;
        #pragma unroll 4
        for (int it = 0; it < 64; ++it) {
            int idx = it * 256 + tid;    // c-major, x fast -> coalesced read
            int c = idx >> 7, x = idx & 127;
            t[x * 130 + c] = (f16)loi[c * NPIX + y * HWD + x];
        }
        __syncthreads();
        #pragma unroll
        for (int it = 0; it < 8; ++it) {
            int j = it * 256 + tid;      // 2048 chunks of 8 f16
            int x = j >> 4, cc = (j & 15) * 8;
            f16x8 v;
            #pragma unroll
            for (int u = 0; u < 8; ++u) v[u] = t[x * 130 + cc + u];
            *(f16x8*)(loiT + (y * HWD + x) * HWD + cc) = v;
        }
    } else if (bid < 640) {
        const int b = bid - 128;         // 0..511
        const float* W = (b < 256) ? W1 : W2;
        f16* Wt = (b < 256) ? W1T : W2T;
        const int bb = b & 255;
        __shared__ f16 t[64 * 66];
        const int k0 = (bb >> 4) * 64;
        const int n0 = (bb & 15) * 64;
        #pragma unroll 4
        for (int it = 0; it < 16; ++it) {
            int i = it * 256 + tid;      // coalesced read over n
            int r = i >> 6, c = i & 63;
            t[c * 66 + r] = (f16)W[(size_t)(k0 + r) * NDIM + n0 + c];
        }
        __syncthreads();
        #pragma unroll
        for (int it = 0; it < 2; ++it) {
            int j = it * 256 + tid;
            int nr = j >> 3, kc = (j & 7) * 8;
            f16x8 v;
            #pragma unroll
            for (int u = 0; u < 8; ++u) v[u] = t[nr * 66 + kc + u];
            const int kk = k0 + kc;      // multiple of 8
            *(f16x8*)(Wt + ((size_t)(kk >> 5) * NDIM + (n0 + nr)) * 32 + (kk & 31)) = v;
        }
    } else if (bid < 704) {
        const int p = (bid - 640) * 256 + tid;   // 64 blocks x 256 = 16384
        const int y = p >> 7, x = p & 127;
        const float c = jloc[p];
        float m = c;
        for (int dy = -1; dy <= 1; ++dy) {
            int yy = y + dy;
            if (yy < 0 || yy >= HWD) continue;
            for (int dx = -1; dx <= 1; ++dx) {
                int xx = x + dx;
                if (xx < 0 || xx >= HWD) continue;
                m = fmaxf(m, jloc[yy * HWD + xx]);
            }
        }
        if (c == m && c > 0.0f) {
            int pos = atomicAdd(count, 1);
            if (pos < MAXCAND) {
                unsigned int ub = __float_as_uint(c);
                cand[pos] = ((unsigned long long)ub << 32) |
                            (unsigned long long)(0xFFFFFFFFu - (unsigned int)p);
            }
        }
    } else {
        const int base = (bid - 704) * 1024 + tid * 4;   // 60 blocks cover 61440
        #pragma unroll
        for (int u = 0; u < 4; ++u)
            if (base + u < out_n) out[base + u] = 0.f;
    }
}

// ---------------------------------------------------------------------------
// Rank-select top-300, LDS-cached. Keys unique => ranks exact; matches
// jax.lax.top_k order (value desc, index asc).
// ---------------------------------------------------------------------------
__global__ __launch_bounds__(256) void rank_junc_kernel(
    const unsigned long long* __restrict__ cand, const int* __restrict__ count,
    const float* __restrict__ joff, float* __restrict__ juncs /* [300][2] */)
{
    __shared__ unsigned long long keys[MAXCAND];   // 32 KB
    const int n = min(*count, MAXCAND);
    const int t = blockIdx.x * 256 + threadIdx.x;  // 16 blocks = 4096 threads
    for (int i = threadIdx.x; i < n; i += 256)
        keys[i] = cand[i];
    __syncthreads();
    if (t >= n) return;
    const unsigned long long key = keys[t];
    int rank = 0;
    int j = 0;
    for (; j + 4 <= n; j += 4) {
        rank += (keys[j]     > key);
        rank += (keys[j + 1] > key);
        rank += (keys[j + 2] > key);
        rank += (keys[j + 3] > key);
    }
    for (; j < n; ++j) rank += (keys[j] > key);
    if (rank < TOPK_N) {
        unsigned int p = 0xFFFFFFFFu - (unsigned int)(key & 0xFFFFFFFFull);
        // x = idx%w + (sigmoid(joff0)-0.5) + 0.5 = idx%w + sigmoid(joff0)
        float sx = 1.0f / (1.0f + expf(-joff[p]));
        float sy = 1.0f / (1.0f + expf(-joff[NPIX + p]));
        juncs[2 * rank + 0] = (float)(p & 127) + sx;
        juncs[2 * rank + 1] = (float)(p >> 7) + sy;
    }
}

// ---------------------------------------------------------------------------
// Per-line sampling, deduplicated: the 4 tap offsets + 4 weights of each of
// the 32 points depend only on the point, not the channel — lanes 0..31
// compute them ONCE into LDS; the channel loop (all 64 lanes, 2 ch each)
// reads them as wave-uniform broadcasts. 4 lines/block (wave per line).
// Output feats in K-chunk-tiled layout (matches GEMM staging).
// ---------------------------------------------------------------------------
__global__ __launch_bounds__(256) void sample_kernel(
    const f16* __restrict__ loiT, const float* __restrict__ juncs,
    const int* __restrict__ edge_idx, f16* __restrict__ feats)
{
    const int wv = threadIdx.x >> 6;
    const int l = blockIdx.x * 4 + wv;
    const int lane = threadIdx.x & 63;

    __shared__ int   soff[4][32][4];   // channel-base element offsets
    __shared__ float swt[4][32][4];    // bilinear weights

    if (lane < 32) {
        const int e0 = edge_idx[2 * l], e1 = edge_idx[2 * l + 1];
        const float ux = juncs[2 * e0], uy = juncs[2 * e0 + 1];
        const float vx = juncs[2 * e1], vy = juncs[2 * e1 + 1];
        const int j = lane;
        const float t = (float)j * (1.0f / 31.0f);
        const float px = ux * t + vx * (1.0f - t) - 0.5f;
        const float py = uy * t + vy * (1.0f - t) - 0.5f;
        float fx0 = fminf(fmaxf(floorf(px), 0.0f), 127.0f);
        float fy0 = fminf(fmaxf(floorf(py), 0.0f), 127.0f);
        float fx1 = fminf(fx0 + 1.0f, 127.0f);
        float fy1 = fminf(fy0 + 1.0f, 127.0f);
        int ix0 = (int)fx0, iy0 = (int)fy0, ix1 = (int)fx1, iy1 = (int)fy1;
        soff[wv][j][0] = (iy0 * HWD + ix0) * HWD;
        soff[wv][j][1] = (iy1 * HWD + ix0) * HWD;
        soff[wv][j][2] = (iy0 * HWD + ix1) * HWD;
        soff[wv][j][3] = (iy1 * HWD + ix1) * HWD;
        swt[wv][j][0] = (fy1 - py) * (fx1 - px);
        swt[wv][j][1] = (py - fy0) * (fx1 - px);
        swt[wv][j][2] = (fy1 - py) * (px - fx0);
        swt[wv][j][3] = (py - fy0) * (px - fx0);
    }
    __syncthreads();

    const int c2 = lane * 2;
    f16x8 o0, o1;
    #pragma unroll
    for (int p = 0; p < 8; ++p) {
        float m0 = -INFINITY, m1 = -INFINITY;
        #pragma unroll
        for (int jj = 0; jj < 4; ++jj) {
            const int j = p * 4 + jj;
            const int b00 = soff[wv][j][0], b10 = soff[wv][j][1];
            const int b01 = soff[wv][j][2], b11 = soff[wv][j][3];
            const float w00 = swt[wv][j][0], w10 = swt[wv][j][1];
            const float w01 = swt[wv][j][2], w11 = swt[wv][j][3];
            f16x2 v00 = *(const f16x2*)(loiT + b00 + c2);
            f16x2 v10 = *(const f16x2*)(loiT + b10 + c2);
            f16x2 v01 = *(const f16x2*)(loiT + b01 + c2);
            f16x2 v11 = *(const f16x2*)(loiT + b11 + c2);
            float s0 = (float)v00.x * w00 + (float)v10.x * w10 +
                       (float)v01.x * w01 + (float)v11.x * w11;
            float s1 = (float)v00.y * w00 + (float)v10.y * w10 +
                       (float)v01.y * w01 + (float)v11.y * w11;
            m0 = fmaxf(m0, s0);
            m1 = fmaxf(m1, s1);
        }
        o0[p] = (f16)m0;   // feature k = 16*lane + p
        o1[p] = (f16)m1;   // feature k = 16*lane + 8 + p
    }
    // tiled: (l, k) -> ((k>>5)*MPAD + l)*32 + (k&31); k-chunk = lane>>1,
    // within-chunk = (lane&1)*16.
    f16* dst = feats + ((size_t)(lane >> 1) * MPAD + l) * 32 + (lane & 1) * 16;
    *(f16x8*)(dst) = o0;
    *(f16x8*)(dst + 8) = o1;
}

// ---------------------------------------------------------------------------
// GEMM: 128x256 tile, 256 threads (2x2 waves of 64x128 subtiles). Two BK=32
// subtiles per round (one vmcnt(0)+barrier drain per 64 MFMAs/wave), operands
// in K-chunk-tiled layout (each staged tile contiguous; G2L = 1KB bursts).
// LDS [row][32] f16 (proven fragment/bank behavior), 48 KiB -> 3 blocks/CU
// (launch_bounds min-waves-per-EU = 3 -> 12 waves/CU; LDS 144/160 KiB).
// Cross-block interleave hides the per-round {G2L, vmcnt(0), barrier}
// serialization (the measured 27 GB/s/CU delivery wall is latency, not BW).
// Grid dim3(4,157), x = nblk FAST: consecutive blocks share the A-panel
// (HBM-fetch A once) and each XCD sees a fixed nblk (B-slice L2-resident).
// head=0: C = relu(A@Bt^T + bias), stored K-chunk-tiled fp16.
// head=1: v = relu(A@Bt^T + bias); out[m][j] += v . W3  (atomicAdd, + b3 once)
// ---------------------------------------------------------------------------
__global__ __launch_bounds__(256, 3) void gemm_bias_relu_kernel(
    const f16* __restrict__ A, const f16* __restrict__ Bt,
    const float* __restrict__ bias, f16* __restrict__ C,
    const float* __restrict__ W3, const float* __restrict__ b3,
    float* __restrict__ out, int K, int head)
{
    const int tid = threadIdx.x;
    const int wave = tid >> 6, lane = tid & 63;
    const int wm = wave >> 1, wn = wave & 1;
    const int m0 = blockIdx.y * 128;             // y = mblk (slow)
    const int n0 = blockIdx.x * 256;             // x = nblk (fast)

    __shared__ f16 sA0[128 * 32];                //  8 KiB
    __shared__ f16 sA1[128 * 32];
    __shared__ f16 sB0[256 * 32];                // 16 KiB
    __shared__ f16 sB1[256 * 32];

    f32x4 acc[4][8];
    #pragma unroll
    for (int mi = 0; mi < 4; ++mi)
        #pragma unroll
        for (int ni = 0; ni < 8; ++ni)
            acc[mi][ni] = (f32x4){0.f, 0.f, 0.f, 0.f};

    // Tiled staging: k-chunk c of A-tile = contiguous 4096 f16 at
    // A + (c*MPAD + m0)*32 (8 segs of 1KB); B-tile = 8192 f16 (16 segs).
    // Wave w stages A segs {w, w+4}, B segs {w, w+4, w+8, w+12};
    // lane i deposits seg_base + i*16B. Global order == LDS order.
    const size_t strideA = (size_t)MPAD * 32;   // f16 per k-chunk
    const size_t strideB = (size_t)NDIM * 32;
    const f16* gA = A + (size_t)m0 * 32 + wave * 512 + lane * 8;
    const f16* gB = Bt + (size_t)n0 * 32 + wave * 512 + lane * 8;
    const int so = wave * 512;                  // + lane*16B implicit

    const int col16 = lane & 15;
    const int kq = (lane >> 4) * 8;

    const int NC = K >> 5;                      // 32 k-chunks
    for (int c0 = 0; c0 < NC; c0 += 2) {
        const f16* a0 = gA + (size_t)c0 * strideA;
        const f16* a1 = a0 + strideA;
        const f16* b0 = gB + (size_t)c0 * strideB;
        const f16* b1 = b0 + strideB;
        __syncthreads();                      // prev round's LDS reads complete
        G2L(a0, sA0 + so);
        G2L(a0 + 2048, sA0 + so + 2048);
        G2L(a1, sA1 + so);
        G2L(a1 + 2048, sA1 + so + 2048);
        G2L(b0, sB0 + so);
        G2L(b0 + 2048, sB0 + so + 2048);
        G2L(b0 + 4096, sB0 + so + 4096);
        G2L(b0 + 6144, sB0 + so + 6144);
        G2L(b1, sB1 + so);
        G2L(b1 + 2048, sB1 + so + 2048);
        G2L(b1 + 4096, sB1 + so + 4096);
        G2L(b1 + 6144, sB1 + so + 6144);
        __builtin_amdgcn_s_waitcnt(0x0f70);   // vmcnt(0): own DMA done
        __syncthreads();                      // all waves' DMA done

        {
            f16x8 af[4], bf[8];
            #pragma unroll
            for (int i = 0; i < 4; ++i)
                af[i] = *(const f16x8*)(sA0 + (wm * 64 + i * 16 + col16) * 32 + kq);
            #pragma unroll
            for (int i = 0; i < 8; ++i)
                bf[i] = *(const f16x8*)(sB0 + (wn * 128 + i * 16 + col16) * 32 + kq);
            #pragma unroll
            for (int mi = 0; mi < 4; ++mi)
                #pragma unroll
                for (int ni = 0; ni < 8; ++ni)
                    acc[mi][ni] = __builtin_amdgcn_mfma_f32_16x16x32_f16(
                        af[mi], bf[ni], acc[mi][ni], 0, 0, 0);
        }
        {
            f16x8 af[4], bf[8];
            #pragma unroll
            for (int i = 0; i < 4; ++i)
                af[i] = *(const f16x8*)(sA1 + (wm * 64 + i * 16 + col16) * 32 + kq);
            #pragma unroll
            for (int i = 0; i < 8; ++i)
                bf[i] = *(const f16x8*)(sB1 + (wn * 128 + i * 16 + col16) * 32 + kq);
            #pragma unroll
            for (int mi = 0; mi < 4; ++mi)
                #pragma unroll
                for (int ni = 0; ni < 8; ++ni)
                    acc[mi][ni] = __builtin_amdgcn_mfma_f32_16x16x32_f16(
                        af[mi], bf[ni], acc[mi][ni], 0, 0, 0);
        }
    }

    const int quad = lane >> 4;
    if (!head) {
        #pragma unroll
        for (int ni = 0; ni < 8; ++ni) {
            const int n = n0 + wn * 128 + ni * 16 + col16;
            const float b = bias[n];
            const size_t cb = ((size_t)(n >> 5) * MPAD) * 32 + (n & 31);
            #pragma unroll
            for (int mi = 0; mi < 4; ++mi) {
                #pragma unroll
                for (int r = 0; r < 4; ++r) {
                    const int m = m0 + wm * 64 + mi * 16 + quad * 4 + r;
                    float v = fmaxf(acc[mi][ni][r] + b, 0.f);
                    C[cb + (size_t)m * 32] = (f16)v;   // K-chunk-tiled
                }
            }
        }
    } else {
        float bb[8], w3c[8][3];
        #pragma unroll
        for (int ni = 0; ni < 8; ++ni) {
            const int n = n0 + wn * 128 + ni * 16 + col16;
            bb[ni] = bias[n];
            #pragma unroll
            for (int jj = 0; jj < 3; ++jj) w3c[ni][jj] = W3[n * 3 + jj];
        }
        const bool addb3 = (blockIdx.x == 0 && wn == 0);
        #pragma unroll
        for (int mi = 0; mi < 4; ++mi) {
            #pragma unroll
            for (int r = 0; r < 4; ++r) {
                float s0 = 0.f, s1 = 0.f, s2 = 0.f;
                #pragma unroll
                for (int ni = 0; ni < 8; ++ni) {
                    float v = fmaxf(acc[mi][ni][r] + bb[ni], 0.f);
                    s0 += v * w3c[ni][0];
                    s1 += v * w3c[ni][1];
                    s2 += v * w3c[ni][2];
                }
                #pragma unroll
                for (int mask = 1; mask <= 8; mask <<= 1) {
                    s0 += __shfl_xor(s0, mask);
                    s1 += __shfl_xor(s1, mask);
                    s2 += __shfl_xor(s2, mask);
                }
                if (col16 == 0) {
                    const int m = m0 + wm * 64 + mi * 16 + quad * 4 + r;
                    if (m < NLINES) {
                        atomicAdd(&out[m * 3 + 0], s0 + (addb3 ? b3[0] : 0.f));
                        atomicAdd(&out[m * 3 + 1], s1 + (addb3 ? b3[1] : 0.f));
                        atomicAdd(&out[m * 3 + 2], s2 + (addb3 ? b3[2] : 0.f));
                    }
                }
            }
        }
    }
}

// ---------------------------------------------------------------------------
extern "C" void kernel_launch(void* const* d_in, const int* in_sizes, int n_in,
                              void* d_out, int out_size, void* d_ws, size_t ws_size,
                              hipStream_t stream)
{
    const float* jloc = (const float*)d_in[0];
    const float* joff = (const float*)d_in[1];
    const float* loi  = (const float*)d_in[2];
    const int*   eidx = (const int*)d_in[3];
    const float* W1   = (const float*)d_in[4];
    const float* b1   = (const float*)d_in[5];
    const float* W2   = (const float*)d_in[6];
    const float* b2   = (const float*)d_in[7];
    const float* W3   = (const float*)d_in[8];
    const float* b3   = (const float*)d_in[9];
    float* out = (float*)d_out;

    char* ws = (char*)d_ws;
    f16*   loiT  = (f16*)(ws);                            // 4 MB
    f16*   W1T   = (f16*)(ws + ((size_t)4 << 20));        // 2 MB
    f16*   W2T   = (f16*)(ws + ((size_t)6 << 20));        // 2 MB
    float* juncs = (float*)(ws + ((size_t)8 << 20));      // 2.4 KB
    int*   count = (int*)(ws + ((size_t)8 << 20) + 4096);
    unsigned long long* cand =
        (unsigned long long*)(ws + ((size_t)8 << 20) + 8192);  // 32 KB
    f16*   feats = (f16*)(ws + ((size_t)9 << 20));        // 40 MB (tiled MPADx1024)
    f16*   h1    = (f16*)(ws + ((size_t)51 << 20));       // 40 MB (tiled)

    hipMemsetAsync(count, 0, sizeof(int), stream);
    preproc_kernel<<<dim3(764), dim3(256), 0, stream>>>(
        loi, loiT, W1, W1T, W2, W2T, jloc, cand, count, out, out_size);
    rank_junc_kernel<<<dim3(MAXCAND / 256), dim3(256), 0, stream>>>(
        cand, count, joff, juncs);
    sample_kernel<<<dim3(NLINES / 4), dim3(256), 0, stream>>>(loiT, juncs, eidx, feats);
    gemm_bias_relu_kernel<<<dim3(NDIM / 256, MPAD / 128), dim3(256), 0, stream>>>(
        feats, W1T, b1, h1, nullptr, nullptr, nullptr, KDIM, 0);
    gemm_bias_relu_kernel<<<dim3(NDIM / 256, MPAD / 128), dim3(256), 0, stream>>>(
        h1, W2T, b2, nullptr, W3, b3, out, KDIM, 1);
}

// Round 5
// 335.862 us; speedup vs baseline: 1.2679x; 1.2679x over previous
//
#include <hip/hip_runtime.h>
#include <cmath>

// ---------------------------------------------------------------------------
// WireframeDetector: NMS -> top-k 300 junctions -> line sampling (bilinear +
// maxpool) -> 3-layer MLP (fp16 MFMA for the two 1024-wide GEMMs).
// R20: B (weights) taken OUT of the G2L+barrier staging path. W1T/W2T stored
//      fragment-major (((c*64+nf)*64+lane)*8) and loaded global->VGPR as
//      coalesced dwordx4, one round ahead, compiler-counted vmcnt, never
//      barrier-drained. Waves 1x4 (128 rows x 64 cols each) -> zero B wave-
//      duplication. Only A (256 KB/block, was 768 KB total) rides G2L:
//      8 x 8KB LDS ring, prefetch distance 2 rounds, uniform counted
//      s_waitcnt vmcnt(12) (in-order retirement => exact), batch order
//      pinned by empty-asm fences. A layout gains the R16-proven XOR slot
//      swizzle (producers: sample store + gemm1 epilogue) -> A ds_reads
//      2-way (free) instead of 8-way conflicts.
//      R19 lesson: launch_bounds(256,3) spilled acc to scratch (WRITE_SIZE
//      15->249 MB) -> bound stays at 2 blocks/CU.
// ---------------------------------------------------------------------------

typedef _Float16 f16;
typedef _Float16 f16x2 __attribute__((ext_vector_type(2)));
typedef _Float16 f16x8 __attribute__((ext_vector_type(8)));
typedef float f32x4 __attribute__((ext_vector_type(4)));

#define HWD 128
#define NPIX 16384            // 128*128
#define TOPK_N 300
#define NLINES 20000
#define MPAD 20096            // 157 * 128
#define KDIM 1024
#define NDIM 1024
#define MAXCAND 4096

// A operand layout (feats, h1), f16 elems:
//   idx(row,k) = ((k>>5)*MPAD + row)*32 + slot(row,k)*8 + (k&7)
//   slot(row,k) = ((k>>3)&3) ^ ((row>>1)&3)       (XOR bank swizzle)
// Each 32-k chunk of 128 rows is a contiguous 8 KiB block == its LDS image.
// B operand layout (W1T, W2T), f16 elems:
//   idx(n,k) = (((k>>5)*64 + (n>>4))*64 + ((k>>3)&3)*16 + (n&15))*8 + (k&7)
// i.e. per (chunk, 16-col frag) the 64 lanes' 16B pieces are contiguous ->
// one global_load_dwordx4 per lane, fully coalesced, no LDS needed.

// async global->LDS, 16B per lane; LDS dest = wave-uniform base + lane*16
#define G2L(gp, lp) __builtin_amdgcn_global_load_lds( \
    (const __attribute__((address_space(1))) void*)(gp), \
    (__attribute__((address_space(3))) void*)(lp), 16, 0, 0)

// ---------------------------------------------------------------------------
// Fused preprocessing, one dispatch of 764 blocks:
//   blocks 0..127   : transpose loi [C][H][W] fp32 -> loiT [H][W][C] fp16
//   blocks 128..639 : W1/W2 [K][N] fp32 -> fragment-major fp16 (see above)
//   blocks 640..703 : 3x3 NMS on jloc, survivors -> cand list
//   blocks 704..763 : zero out[60000] (consumed by gemm2's atomicAdd epilogue)
// ---------------------------------------------------------------------------
__global__ __launch_bounds__(256) void preproc_kernel(
    const float* __restrict__ loi, f16* __restrict__ loiT,
    const float* __restrict__ W1, f16* __restrict__ W1T,
    const float* __restrict__ W2, f16* __restrict__ W2T,
    const float* __restrict__ jloc, unsigned long long* __restrict__ cand,
    int* __restrict__ count, float* __restrict__ out, int out_n)
{
    const int bid = blockIdx.x;
    const int tid = threadIdx.x;
    if (bid < 128) {
        __shared__ f16 t[128 * 130];     // [x][c], +2 pad kills bank conflicts
        const int y = bid;
        #pragma unroll 4
        for (int it = 0; it < 64; ++it) {
            int idx = it * 256 + tid;    // c-major, x fast -> coalesced read
            int c = idx >> 7, x = idx & 127;
            t[x * 130 + c] = (f16)loi[c * NPIX + y * HWD + x];
        }
        __syncthreads();
        #pragma unroll
        for (int it = 0; it < 8; ++it) {
            int j = it * 256 + tid;      // 2048 chunks of 8 f16
            int x = j >> 4, cc = (j & 15) * 8;
            f16x8 v;
            #pragma unroll
            for (int u = 0; u < 8; ++u) v[u] = t[x * 130 + cc + u];
            *(f16x8*)(loiT + (y * HWD + x) * HWD + cc) = v;
        }
    } else if (bid < 640) {
        const int b = bid - 128;         // 0..511
        const float* W = (b < 256) ? W1 : W2;
        f16* Wt = (b < 256) ? W1T : W2T;
        const int bb = b & 255;
        __shared__ f16 t[64 * 66];
        const int k0 = (bb >> 4) * 64;
        const int n0 = (bb & 15) * 64;
        #pragma unroll 4
        for (int it = 0; it < 16; ++it) {
            int i = it * 256 + tid;      // coalesced read over n
            int r = i >> 6, c = i & 63;
            t[c * 66 + r] = (f16)W[(size_t)(k0 + r) * NDIM + n0 + c];
        }
        __syncthreads();
        #pragma unroll
        for (int it = 0; it < 2; ++it) {
            int j = it * 256 + tid;
            int nr = j >> 3, kc = (j & 7) * 8;
            f16x8 v;
            #pragma unroll
            for (int u = 0; u < 8; ++u) v[u] = t[nr * 66 + kc + u];
            const int kk = k0 + kc;      // multiple of 8
            const int n = n0 + nr;
            *(f16x8*)(Wt + ((size_t)((kk >> 5) * 64 + (n >> 4)) * 64
                            + ((kk >> 3) & 3) * 16 + (n & 15)) * 8) = v;
        }
    } else if (bid < 704) {
        const int p = (bid - 640) * 256 + tid;   // 64 blocks x 256 = 16384
        const int y = p >> 7, x = p & 127;
        const float c = jloc[p];
        float m = c;
        for (int dy = -1; dy <= 1; ++dy) {
            int yy = y + dy;
            if (yy < 0 || yy >= HWD) continue;
            for (int dx = -1; dx <= 1; ++dx) {
                int xx = x + dx;
                if (xx < 0 || xx >= HWD) continue;
                m = fmaxf(m, jloc[yy * HWD + xx]);
            }
        }
        if (c == m && c > 0.0f) {
            int pos = atomicAdd(count, 1);
            if (pos < MAXCAND) {
                unsigned int ub = __float_as_uint(c);
                cand[pos] = ((unsigned long long)ub << 32) |
                            (unsigned long long)(0xFFFFFFFFu - (unsigned int)p);
            }
        }
    } else {
        const int base = (bid - 704) * 1024 + tid * 4;   // 60 blocks cover 61440
        #pragma unroll
        for (int u = 0; u < 4; ++u)
            if (base + u < out_n) out[base + u] = 0.f;
    }
}

// ---------------------------------------------------------------------------
// Rank-select top-300, LDS-cached. Keys unique => ranks exact; matches
// jax.lax.top_k order (value desc, index asc).
// ---------------------------------------------------------------------------
__global__ __launch_bounds__(256) void rank_junc_kernel(
    const unsigned long long* __restrict__ cand, const int* __restrict__ count,
    const float* __restrict__ joff, float* __restrict__ juncs /* [300][2] */)
{
    __shared__ unsigned long long keys[MAXCAND];   // 32 KB
    const int n = min(*count, MAXCAND);
    const int t = blockIdx.x * 256 + threadIdx.x;  // 16 blocks = 4096 threads
    for (int i = threadIdx.x; i < n; i += 256)
        keys[i] = cand[i];
    __syncthreads();
    if (t >= n) return;
    const unsigned long long key = keys[t];
    int rank = 0;
    int j = 0;
    for (; j + 4 <= n; j += 4) {
        rank += (keys[j]     > key);
        rank += (keys[j + 1] > key);
        rank += (keys[j + 2] > key);
        rank += (keys[j + 3] > key);
    }
    for (; j < n; ++j) rank += (keys[j] > key);
    if (rank < TOPK_N) {
        unsigned int p = 0xFFFFFFFFu - (unsigned int)(key & 0xFFFFFFFFull);
        // x = idx%w + (sigmoid(joff0)-0.5) + 0.5 = idx%w + sigmoid(joff0)
        float sx = 1.0f / (1.0f + expf(-joff[p]));
        float sy = 1.0f / (1.0f + expf(-joff[NPIX + p]));
        juncs[2 * rank + 0] = (float)(p & 127) + sx;
        juncs[2 * rank + 1] = (float)(p >> 7) + sy;
    }
}

// ---------------------------------------------------------------------------
// Per-line sampling, deduplicated: lanes 0..31 compute the 4 tap offsets +
// weights of the 32 points once into LDS; channel loop (64 lanes, 2 ch each)
// reads them as wave-uniform broadcasts. 4 lines/block (wave per line).
// Output feats in the XOR-swizzled A operand layout.
// ---------------------------------------------------------------------------
__global__ __launch_bounds__(256) void sample_kernel(
    const f16* __restrict__ loiT, const float* __restrict__ juncs,
    const int* __restrict__ edge_idx, f16* __restrict__ feats)
{
    const int wv = threadIdx.x >> 6;
    const int l = blockIdx.x * 4 + wv;
    const int lane = threadIdx.x & 63;

    __shared__ int   soff[4][32][4];   // channel-base element offsets
    __shared__ float swt[4][32][4];    // bilinear weights

    if (lane < 32) {
        const int e0 = edge_idx[2 * l], e1 = edge_idx[2 * l + 1];
        const float ux = juncs[2 * e0], uy = juncs[2 * e0 + 1];
        const float vx = juncs[2 * e1], vy = juncs[2 * e1 + 1];
        const int j = lane;
        const float t = (float)j * (1.0f / 31.0f);
        const float px = ux * t + vx * (1.0f - t) - 0.5f;
        const float py = uy * t + vy * (1.0f - t) - 0.5f;
        float fx0 = fminf(fmaxf(floorf(px), 0.0f), 127.0f);
        float fy0 = fminf(fmaxf(floorf(py), 0.0f), 127.0f);
        float fx1 = fminf(fx0 + 1.0f, 127.0f);
        float fy1 = fminf(fy0 + 1.0f, 127.0f);
        int ix0 = (int)fx0, iy0 = (int)fy0, ix1 = (int)fx1, iy1 = (int)fy1;
        soff[wv][j][0] = (iy0 * HWD + ix0) * HWD;
        soff[wv][j][1] = (iy1 * HWD + ix0) * HWD;
        soff[wv][j][2] = (iy0 * HWD + ix1) * HWD;
        soff[wv][j][3] = (iy1 * HWD + ix1) * HWD;
        swt[wv][j][0] = (fy1 - py) * (fx1 - px);
        swt[wv][j][1] = (py - fy0) * (fx1 - px);
        swt[wv][j][2] = (fy1 - py) * (px - fx0);
        swt[wv][j][3] = (py - fy0) * (px - fx0);
    }
    __syncthreads();

    const int c2 = lane * 2;
    f16x8 o0, o1;
    #pragma unroll
    for (int p = 0; p < 8; ++p) {
        float m0 = -INFINITY, m1 = -INFINITY;
        #pragma unroll
        for (int jj = 0; jj < 4; ++jj) {
            const int j = p * 4 + jj;
            const int b00 = soff[wv][j][0], b10 = soff[wv][j][1];
            const int b01 = soff[wv][j][2], b11 = soff[wv][j][3];
            const float w00 = swt[wv][j][0], w10 = swt[wv][j][1];
            const float w01 = swt[wv][j][2], w11 = swt[wv][j][3];
            f16x2 v00 = *(const f16x2*)(loiT + b00 + c2);
            f16x2 v10 = *(const f16x2*)(loiT + b10 + c2);
            f16x2 v01 = *(const f16x2*)(loiT + b01 + c2);
            f16x2 v11 = *(const f16x2*)(loiT + b11 + c2);
            float s0 = (float)v00.x * w00 + (float)v10.x * w10 +
                       (float)v01.x * w01 + (float)v11.x * w11;
            float s1 = (float)v00.y * w00 + (float)v10.y * w10 +
                       (float)v01.y * w01 + (float)v11.y * w11;
            m0 = fmaxf(m0, s0);
            m1 = fmaxf(m1, s1);
        }
        o0[p] = (f16)m0;   // feature k = 16*lane + p
        o1[p] = (f16)m1;   // feature k = 16*lane + 8 + p
    }
    // A layout: chunk = lane>>1; o0 oct = 2*(lane&1), o1 oct = 2*(lane&1)+1;
    // slot = oct ^ ((l>>1)&3).
    const int rs = (l >> 1) & 3;
    const int oct0 = (lane & 1) * 2;
    f16* base = feats + ((size_t)(lane >> 1) * MPAD + l) * 32;
    *(f16x8*)(base + ((oct0 ^ rs) * 8)) = o0;
    *(f16x8*)(base + (((oct0 + 1) ^ rs) * 8)) = o1;
}

// ---------------------------------------------------------------------------
// GEMM: 128x256 tile, 256 threads, 4 waves 1x4 (each: all 128 rows x 64 cols,
// acc[8][4]). Per round (2 chunks = BK 64, 16 rounds):
//   s_waitcnt vmcnt(12); s_barrier;            <- counted: only forces A of
//                                                 THIS round (staged 2 rounds
//                                                 ago); last round's 12 vmem
//                                                 ops stay in flight
//   load B(next round) global->VGPR (8x dwordx4, coalesced, no LDS);
//   G2L A(round+2) -> 8-buffer LDS ring;
//   ds_read af (XOR-swizzled, 2-way=free) + 64 MFMA.
// Issue order pinned with empty-asm fences so the vmcnt counts are exact
// (in-order retirement, m135). B loads are waited by compiler-counted vmcnt
// at their MFMA use -- the barrier never drains them.
// head=0: C = relu(A@Bt^T + bias), stored in swizzled A layout fp16.
// head=1: v = relu(A@Bt^T + bias); out[m][j] += v . W3  (atomicAdd, + b3 once)
// ---------------------------------------------------------------------------
__device__ __forceinline__ void chunk_mfma(
    const f16* sA, int aoff, const f16x8 bf[4], f32x4 (&acc)[8][4])
{
    const f16* pA = sA + aoff;
    f16x8 af[4];
    #pragma unroll
    for (int i = 0; i < 4; ++i)
        af[i] = *(const f16x8*)(pA + i * 512);          // rows i*16+col16
    #pragma unroll
    for (int mi = 0; mi < 4; ++mi)
        #pragma unroll
        for (int ni = 0; ni < 4; ++ni)
            acc[mi][ni] = __builtin_amdgcn_mfma_f32_16x16x32_f16(
                af[mi], bf[ni], acc[mi][ni], 0, 0, 0);
    #pragma unroll
    for (int i = 0; i < 4; ++i)
        af[i] = *(const f16x8*)(pA + (4 + i) * 512);    // rows (4+i)*16+col16
    #pragma unroll
    for (int mi = 0; mi < 4; ++mi)
        #pragma unroll
        for (int ni = 0; ni < 4; ++ni)
            acc[4 + mi][ni] = __builtin_amdgcn_mfma_f32_16x16x32_f16(
                af[mi], bf[ni], acc[4 + mi][ni], 0, 0, 0);
}

__global__ __launch_bounds__(256, 2) void gemm_bias_relu_kernel(
    const f16* __restrict__ A, const f16* __restrict__ Bt,
    const float* __restrict__ bias, f16* __restrict__ C,
    const float* __restrict__ W3, const float* __restrict__ b3,
    float* __restrict__ out, int K, int head)
{
    extern __shared__ f16 sbuf[];                // 8 x 4096 f16 = 64 KiB ring
    const int tid = threadIdx.x;
    const int wave = tid >> 6, lane = tid & 63;
    const int wn = wave;                         // wave = column quarter
    const int m0 = blockIdx.y * 128;             // y = mblk (slow)
    const int n0 = blockIdx.x * 256;             // x = nblk (fast)

    const int col16 = lane & 15;
    const int quad = lane >> 4;
    const int aoff = col16 * 32 + ((quad ^ ((col16 >> 1) & 3)) * 8);

    f32x4 acc[8][4];
    #pragma unroll
    for (int mi = 0; mi < 8; ++mi)
        #pragma unroll
        for (int ni = 0; ni < 4; ++ni)
            acc[mi][ni] = (f32x4){0.f, 0.f, 0.f, 0.f};

    const size_t strideA = (size_t)MPAD * 32;    // f16 per k-chunk
    const f16* gA = A + (size_t)m0 * 32 + lane * 8;
    const f16* gB = Bt + ((size_t)(blockIdx.x * 16 + wn * 4) * 64 + lane) * 8;
    const int s0 = wave * 512, s1 = (wave + 4) * 512;

#define STAGE_A(CN) do { \
        const f16* ga_ = gA + (size_t)(CN) * strideA; \
        f16* la_ = sbuf + ((CN) & 7) * 4096; \
        G2L(ga_ + s0, la_ + s0); \
        G2L(ga_ + s1, la_ + s1); \
    } while (0)

#define LOADB(CN, DST) do { \
        const f16* gb_ = gB + (size_t)(CN) * 32768; \
        DST[0] = *(const f16x8*)(gb_); \
        DST[1] = *(const f16x8*)(gb_ + 512); \
        DST[2] = *(const f16x8*)(gb_ + 1024); \
        DST[3] = *(const f16x8*)(gb_ + 1536); \
    } while (0)

#define ROUND(J, CUR, NXT, DO_STAGE, DO_LOADB, WSTR) do { \
        asm volatile(WSTR ::: "memory"); \
        __builtin_amdgcn_s_barrier(); \
        if (DO_LOADB) { LOADB(2 * (J) + 2, NXT[0]); LOADB(2 * (J) + 3, NXT[1]); } \
        asm volatile("" ::: "memory"); \
        if (DO_STAGE) { STAGE_A(2 * (J) + 4); STAGE_A(2 * (J) + 5); } \
        asm volatile("" ::: "memory"); \
        chunk_mfma(sbuf + ((2 * (J)) & 7) * 4096, aoff, CUR[0], acc); \
        chunk_mfma(sbuf + ((2 * (J) + 1) & 7) * 4096, aoff, CUR[1], acc); \
    } while (0)

    f16x8 bfA[2][4], bfB[2][4];

    // Prologue (order pinned: A(0),A(1) are the 4 oldest vmem ops).
    STAGE_A(0); STAGE_A(1);
    asm volatile("" ::: "memory");
    LOADB(0, bfA[0]); LOADB(1, bfA[1]);
    asm volatile("" ::: "memory");
    STAGE_A(2); STAGE_A(3);

    // 16 rounds of 2 chunks. Round j consumes A(2j),A(2j+1) + bf(cur);
    // stages A(2j+4),A(2j+5); loads B(2j+2),B(2j+3).
    for (int jj = 0; jj < 7; ++jj) {
        ROUND(2 * jj,     bfA, bfB, 1, 1, "s_waitcnt vmcnt(12)");
        ROUND(2 * jj + 1, bfB, bfA, 1, 1, "s_waitcnt vmcnt(12)");
    }
    ROUND(14, bfA, bfB, 0, 1, "s_waitcnt vmcnt(12)");
    ROUND(15, bfB, bfA, 0, 0, "s_waitcnt vmcnt(8)");

#undef ROUND
#undef LOADB
#undef STAGE_A

    if (!head) {
        #pragma unroll
        for (int ni = 0; ni < 4; ++ni) {
            const int n = n0 + wn * 64 + ni * 16 + col16;
            const float b = bias[n];
            const size_t rb = (size_t)(n >> 5) * MPAD;
            const int noct = (n >> 3) & 3, ne = n & 7;
            #pragma unroll
            for (int mi = 0; mi < 8; ++mi) {
                #pragma unroll
                for (int r = 0; r < 4; ++r) {
                    const int m = m0 + mi * 16 + quad * 4 + r;
                    float v = fmaxf(acc[mi][ni][r] + b, 0.f);
                    C[(rb + m) * 32 + ((noct ^ ((m >> 1) & 3)) * 8) + ne] = (f16)v;
                }
            }
        }
    } else {
        float bb[4], w3c[4][3];
        #pragma unroll
        for (int ni = 0; ni < 4; ++ni) {
            const int n = n0 + wn * 64 + ni * 16 + col16;
            bb[ni] = bias[n];
            #pragma unroll
            for (int jj = 0; jj < 3; ++jj) w3c[ni][jj] = W3[n * 3 + jj];
        }
        const bool addb3 = (blockIdx.x == 0 && wn == 0);
        #pragma unroll
        for (int mi = 0; mi < 8; ++mi) {
            #pragma unroll
            for (int r = 0; r < 4; ++r) {
                float s0 = 0.f, s1 = 0.f, s2 = 0.f;
                #pragma unroll
                for (int ni = 0; ni < 4; ++ni) {
                    float v = fmaxf(acc[mi][ni][r] + bb[ni], 0.f);
                    s0 += v * w3c[ni][0];
                    s1 += v * w3c[ni][1];
                    s2 += v * w3c[ni][2];
                }
                #pragma unroll
                for (int mask = 1; mask <= 8; mask <<= 1) {
                    s0 += __shfl_xor(s0, mask);
                    s1 += __shfl_xor(s1, mask);
                    s2 += __shfl_xor(s2, mask);
                }
                if (col16 == 0) {
                    const int m = m0 + mi * 16 + quad * 4 + r;
                    if (m < NLINES) {
                        atomicAdd(&out[m * 3 + 0], s0 + (addb3 ? b3[0] : 0.f));
                        atomicAdd(&out[m * 3 + 1], s1 + (addb3 ? b3[1] : 0.f));
                        atomicAdd(&out[m * 3 + 2], s2 + (addb3 ? b3[2] : 0.f));
                    }
                }
            }
        }
    }
}

// ---------------------------------------------------------------------------
extern "C" void kernel_launch(void* const* d_in, const int* in_sizes, int n_in,
                              void* d_out, int out_size, void* d_ws, size_t ws_size,
                              hipStream_t stream)
{
    const float* jloc = (const float*)d_in[0];
    const float* joff = (const float*)d_in[1];
    const float* loi  = (const float*)d_in[2];
    const int*   eidx = (const int*)d_in[3];
    const float* W1   = (const float*)d_in[4];
    const float* b1   = (const float*)d_in[5];
    const float* W2   = (const float*)d_in[6];
    const float* b2   = (const float*)d_in[7];
    const float* W3   = (const float*)d_in[8];
    const float* b3   = (const float*)d_in[9];
    float* out = (float*)d_out;

    char* ws = (char*)d_ws;
    f16*   loiT  = (f16*)(ws);                            // 4 MB
    f16*   W1T   = (f16*)(ws + ((size_t)4 << 20));        // 2 MB
    f16*   W2T   = (f16*)(ws + ((size_t)6 << 20));        // 2 MB
    float* juncs = (float*)(ws + ((size_t)8 << 20));      // 2.4 KB
    int*   count = (int*)(ws + ((size_t)8 << 20) + 4096);
    unsigned long long* cand =
        (unsigned long long*)(ws + ((size_t)8 << 20) + 8192);  // 32 KB
    f16*   feats = (f16*)(ws + ((size_t)9 << 20));        // 40 MB (tiled MPADx1024)
    f16*   h1    = (f16*)(ws + ((size_t)51 << 20));       // 40 MB (tiled)

    static int attr_done = 0;
    if (!attr_done) {
        (void)hipFuncSetAttribute(
            reinterpret_cast<const void*>(&gemm_bias_relu_kernel),
            hipFuncAttributeMaxDynamicSharedMemorySize, 65536);
        attr_done = 1;
    }

    hipMemsetAsync(count, 0, sizeof(int), stream);
    preproc_kernel<<<dim3(764), dim3(256), 0, stream>>>(
        loi, loiT, W1, W1T, W2, W2T, jloc, cand, count, out, out_size);
    rank_junc_kernel<<<dim3(MAXCAND / 256), dim3(256), 0, stream>>>(
        cand, count, joff, juncs);
    sample_kernel<<<dim3(NLINES / 4), dim3(256), 0, stream>>>(loiT, juncs, eidx, feats);
    gemm_bias_relu_kernel<<<dim3(NDIM / 256, MPAD / 128), dim3(256), 65536, stream>>>(
        feats, W1T, b1, h1, nullptr, nullptr, nullptr, KDIM, 0);
    gemm_bias_relu_kernel<<<dim3(NDIM / 256, MPAD / 128), dim3(256), 65536, stream>>>(
        h1, W2T, b2, nullptr, W3, b3, out, KDIM, 1);
}

// Round 6
// 292.433 us; speedup vs baseline: 1.4561x; 1.1485x over previous
//
#include <hip/hip_runtime.h>
#include <cmath>

// ---------------------------------------------------------------------------
// WireframeDetector: NMS -> top-k 300 junctions -> line sampling (bilinear +
// maxpool) -> 3-layer MLP (fp16 MFMA for the two 1024-wide GEMMs).
// R21: combine the two proven-good ingredients that were never tested
//      together: (a) R18's 2-blocks/CU 128x256 4-wave structure (85 us, the
//      best measured), (b) R17's counted-vmcnt distance-2 prefetch (proven
//      correct, but tested only at 1 block/CU where it had no overlap
//      partner). Ring of 3 x 24 KiB round-buffers (72 KiB LDS -> still 2
//      blocks/CU), per round {vmcnt(6); barrier; STAGE(c+2); ds_read; 32
//      MFMA} -- vmcnt never drains to 0 except the last round. Both A and B
//      operands carry the XOR slot swizzle (R16/R20-proven, conflicts = 0):
//      producers write swizzled, G2L stays linear, reads add a lane-constant
//      offset. Scorecard so far: R18 drain-0 2blk = 85; R17 counted 1blk =
//      123; R20 B-direct = 114. This tests the last untried quadrant.
// ---------------------------------------------------------------------------

typedef _Float16 f16;
typedef _Float16 f16x2 __attribute__((ext_vector_type(2)));
typedef _Float16 f16x8 __attribute__((ext_vector_type(8)));
typedef float f32x4 __attribute__((ext_vector_type(4)));

#define HWD 128
#define NPIX 16384            // 128*128
#define TOPK_N 300
#define NLINES 20000
#define MPAD 20096            // 157 * 128
#define KDIM 1024
#define NDIM 1024
#define MAXCAND 4096

// A operand layout (feats, h1), f16 elems:
//   idx(row,k) = ((k>>5)*MPAD + row)*32 + slot(row,k)*8 + (k&7)
//   slot(row,k) = ((k>>3)&3) ^ ((row>>1)&3)       (XOR bank swizzle)
// B operand layout (W1T, W2T): same with row->n, MPAD->1024:
//   idx(n,k)   = ((k>>5)*1024 + n)*32 + slot(n,k)*8 + (k&7)
// Each 32-k chunk is contiguous (A: 8 KiB per 128 rows, B: 16 KiB per 256
// rows) and IS the LDS image. Fragment ds_read_b128 offset is lane-constant:
// swz = (quad ^ ((col16>>1)&3))*8  (row blocks are multiples of 8).

// async global->LDS, 16B per lane; LDS dest = wave-uniform base + lane*16
#define G2L(gp, lp) __builtin_amdgcn_global_load_lds( \
    (const __attribute__((address_space(1))) void*)(gp), \
    (__attribute__((address_space(3))) void*)(lp), 16, 0, 0)

// ---------------------------------------------------------------------------
// Fused preprocessing, one dispatch of 764 blocks:
//   blocks 0..127   : transpose loi [C][H][W] fp32 -> loiT [H][W][C] fp16
//   blocks 128..639 : W1/W2 [K][N] fp32 -> swizzled K-chunk-tiled fp16
//   blocks 640..703 : 3x3 NMS on jloc, survivors -> cand list
//   blocks 704..763 : zero out[60000] (consumed by gemm2's atomicAdd epilogue)
// ---------------------------------------------------------------------------
__global__ __launch_bounds__(256) void preproc_kernel(
    const float* __restrict__ loi, f16* __restrict__ loiT,
    const float* __restrict__ W1, f16* __restrict__ W1T,
    const float* __restrict__ W2, f16* __restrict__ W2T,
    const float* __restrict__ jloc, unsigned long long* __restrict__ cand,
    int* __restrict__ count, float* __restrict__ out, int out_n)
{
    const int bid = blockIdx.x;
    const int tid = threadIdx.x;
    if (bid < 128) {
        __shared__ f16 t[128 * 130];     // [x][c], +2 pad kills bank conflicts
        const int y = bid;
        #pragma unroll 4
        for (int it = 0; it < 64; ++it) {
            int idx = it * 256 + tid;    // c-major, x fast -> coalesced read
            int c = idx >> 7, x = idx & 127;
            t[x * 130 + c] = (f16)loi[c * NPIX + y * HWD + x];
        }
        __syncthreads();
        #pragma unroll
        for (int it = 0; it < 8; ++it) {
            int j = it * 256 + tid;      // 2048 chunks of 8 f16
            int x = j >> 4, cc = (j & 15) * 8;
            f16x8 v;
            #pragma unroll
            for (int u = 0; u < 8; ++u) v[u] = t[x * 130 + cc + u];
            *(f16x8*)(loiT + (y * HWD + x) * HWD + cc) = v;
        }
    } else if (bid < 640) {
        const int b = bid - 128;         // 0..511
        const float* W = (b < 256) ? W1 : W2;
        f16* Wt = (b < 256) ? W1T : W2T;
        const int bb = b & 255;
        __shared__ f16 t[64 * 66];
        const int k0 = (bb >> 4) * 64;
        const int n0 = (bb & 15) * 64;
        #pragma unroll 4
        for (int it = 0; it < 16; ++it) {
            int i = it * 256 + tid;      // coalesced read over n
            int r = i >> 6, c = i & 63;
            t[c * 66 + r] = (f16)W[(size_t)(k0 + r) * NDIM + n0 + c];
        }
        __syncthreads();
        #pragma unroll
        for (int it = 0; it < 2; ++it) {
            int j = it * 256 + tid;
            int nr = j >> 3, kc = (j & 7) * 8;
            f16x8 v;
            #pragma unroll
            for (int u = 0; u < 8; ++u) v[u] = t[nr * 66 + kc + u];
            const int kk = k0 + kc;      // multiple of 8
            const int n = n0 + nr;
            const int slot = ((kk >> 3) & 3) ^ ((n >> 1) & 3);
            *(f16x8*)(Wt + ((size_t)(kk >> 5) * NDIM + n) * 32 + slot * 8) = v;
        }
    } else if (bid < 704) {
        const int p = (bid - 640) * 256 + tid;   // 64 blocks x 256 = 16384
        const int y = p >> 7, x = p & 127;
        const float c = jloc[p];
        float m = c;
        for (int dy = -1; dy <= 1; ++dy) {
            int yy = y + dy;
            if (yy < 0 || yy >= HWD) continue;
            for (int dx = -1; dx <= 1; ++dx) {
                int xx = x + dx;
                if (xx < 0 || xx >= HWD) continue;
                m = fmaxf(m, jloc[yy * HWD + xx]);
            }
        }
        if (c == m && c > 0.0f) {
            int pos = atomicAdd(count, 1);
            if (pos < MAXCAND) {
                unsigned int ub = __float_as_uint(c);
                cand[pos] = ((unsigned long long)ub << 32) |
                            (unsigned long long)(0xFFFFFFFFu - (unsigned int)p);
            }
        }
    } else {
        const int base = (bid - 704) * 1024 + tid * 4;   // 60 blocks cover 61440
        #pragma unroll
        for (int u = 0; u < 4; ++u)
            if (base + u < out_n) out[base + u] = 0.f;
    }
}

// ---------------------------------------------------------------------------
// Rank-select top-300, LDS-cached. Keys unique => ranks exact; matches
// jax.lax.top_k order (value desc, index asc).
// ---------------------------------------------------------------------------
__global__ __launch_bounds__(256) void rank_junc_kernel(
    const unsigned long long* __restrict__ cand, const int* __restrict__ count,
    const float* __restrict__ joff, float* __restrict__ juncs /* [300][2] */)
{
    __shared__ unsigned long long keys[MAXCAND];   // 32 KB
    const int n = min(*count, MAXCAND);
    const int t = blockIdx.x * 256 + threadIdx.x;  // 16 blocks = 4096 threads
    for (int i = threadIdx.x; i < n; i += 256)
        keys[i] = cand[i];
    __syncthreads();
    if (t >= n) return;
    const unsigned long long key = keys[t];
    int rank = 0;
    int j = 0;
    for (; j + 4 <= n; j += 4) {
        rank += (keys[j]     > key);
        rank += (keys[j + 1] > key);
        rank += (keys[j + 2] > key);
        rank += (keys[j + 3] > key);
    }
    for (; j < n; ++j) rank += (keys[j] > key);
    if (rank < TOPK_N) {
        unsigned int p = 0xFFFFFFFFu - (unsigned int)(key & 0xFFFFFFFFull);
        // x = idx%w + (sigmoid(joff0)-0.5) + 0.5 = idx%w + sigmoid(joff0)
        float sx = 1.0f / (1.0f + expf(-joff[p]));
        float sy = 1.0f / (1.0f + expf(-joff[NPIX + p]));
        juncs[2 * rank + 0] = (float)(p & 127) + sx;
        juncs[2 * rank + 1] = (float)(p >> 7) + sy;
    }
}

// ---------------------------------------------------------------------------
// Per-line sampling, deduplicated: lanes 0..31 compute the 4 tap offsets +
// weights of the 32 points once into LDS; channel loop (64 lanes, 2 ch each)
// reads them as wave-uniform broadcasts. 4 lines/block (wave per line).
// Output feats in the XOR-swizzled A operand layout.
// ---------------------------------------------------------------------------
__global__ __launch_bounds__(256) void sample_kernel(
    const f16* __restrict__ loiT, const float* __restrict__ juncs,
    const int* __restrict__ edge_idx, f16* __restrict__ feats)
{
    const int wv = threadIdx.x >> 6;
    const int l = blockIdx.x * 4 + wv;
    const int lane = threadIdx.x & 63;

    __shared__ int   soff[4][32][4];   // channel-base element offsets
    __shared__ float swt[4][32][4];    // bilinear weights

    if (lane < 32) {
        const int e0 = edge_idx[2 * l], e1 = edge_idx[2 * l + 1];
        const float ux = juncs[2 * e0], uy = juncs[2 * e0 + 1];
        const float vx = juncs[2 * e1], vy = juncs[2 * e1 + 1];
        const int j = lane;
        const float t = (float)j * (1.0f / 31.0f);
        const float px = ux * t + vx * (1.0f - t) - 0.5f;
        const float py = uy * t + vy * (1.0f - t) - 0.5f;
        float fx0 = fminf(fmaxf(floorf(px), 0.0f), 127.0f);
        float fy0 = fminf(fmaxf(floorf(py), 0.0f), 127.0f);
        float fx1 = fminf(fx0 + 1.0f, 127.0f);
        float fy1 = fminf(fy0 + 1.0f, 127.0f);
        int ix0 = (int)fx0, iy0 = (int)fy0, ix1 = (int)fx1, iy1 = (int)fy1;
        soff[wv][j][0] = (iy0 * HWD + ix0) * HWD;
        soff[wv][j][1] = (iy1 * HWD + ix0) * HWD;
        soff[wv][j][2] = (iy0 * HWD + ix1) * HWD;
        soff[wv][j][3] = (iy1 * HWD + ix1) * HWD;
        swt[wv][j][0] = (fy1 - py) * (fx1 - px);
        swt[wv][j][1] = (py - fy0) * (fx1 - px);
        swt[wv][j][2] = (fy1 - py) * (px - fx0);
        swt[wv][j][3] = (py - fy0) * (px - fx0);
    }
    __syncthreads();

    const int c2 = lane * 2;
    f16x8 o0, o1;
    #pragma unroll
    for (int p = 0; p < 8; ++p) {
        float m0 = -INFINITY, m1 = -INFINITY;
        #pragma unroll
        for (int jj = 0; jj < 4; ++jj) {
            const int j = p * 4 + jj;
            const int b00 = soff[wv][j][0], b10 = soff[wv][j][1];
            const int b01 = soff[wv][j][2], b11 = soff[wv][j][3];
            const float w00 = swt[wv][j][0], w10 = swt[wv][j][1];
            const float w01 = swt[wv][j][2], w11 = swt[wv][j][3];
            f16x2 v00 = *(const f16x2*)(loiT + b00 + c2);
            f16x2 v10 = *(const f16x2*)(loiT + b10 + c2);
            f16x2 v01 = *(const f16x2*)(loiT + b01 + c2);
            f16x2 v11 = *(const f16x2*)(loiT + b11 + c2);
            float s0 = (float)v00.x * w00 + (float)v10.x * w10 +
                       (float)v01.x * w01 + (float)v11.x * w11;
            float s1 = (float)v00.y * w00 + (float)v10.y * w10 +
                       (float)v01.y * w01 + (float)v11.y * w11;
            m0 = fmaxf(m0, s0);
            m1 = fmaxf(m1, s1);
        }
        o0[p] = (f16)m0;   // feature k = 16*lane + p
        o1[p] = (f16)m1;   // feature k = 16*lane + 8 + p
    }
    // A layout: chunk = lane>>1; o0 oct = 2*(lane&1), o1 oct = 2*(lane&1)+1;
    // slot = oct ^ ((l>>1)&3).
    const int rs = (l >> 1) & 3;
    const int oct0 = (lane & 1) * 2;
    f16* base = feats + ((size_t)(lane >> 1) * MPAD + l) * 32;
    *(f16x8*)(base + ((oct0 ^ rs) * 8)) = o0;
    *(f16x8*)(base + (((oct0 + 1) ^ rs) * 8)) = o1;
}

// ---------------------------------------------------------------------------
// GEMM: 128x256 tile, 256 threads, 2x2 waves (each 64 rows x 128 cols,
// acc[4][8]). 32 rounds of one BK=32 chunk. Ring of 3 round-buffers
// (24 KiB each: A 8 KiB + B 16 KiB), prefetch distance 2. Per round:
//   s_waitcnt vmcnt(6)   <- forces THIS round's buffer (staged 2 rounds ago);
//                           next round's 6 G2L stay in flight. Last round
//                           drains vmcnt(0).
//   s_barrier            <- also proves all waves done reading buf (c-1)%3
//   STAGE(c+2)           <- 6 G2L into buffer (c+2)%3 (distinct mod 3)
//   ds_read af[4]/bf[8] (XOR-swizzled, conflict-free) + 32 MFMA
// LDS 72 KiB -> 2 blocks/CU (cross-block interleave preserved).
// head=0: C = relu(A@Bt^T + bias), stored in swizzled A layout fp16.
// head=1: v = relu(A@Bt^T + bias); out[m][j] += v . W3  (atomicAdd, + b3 once)
// ---------------------------------------------------------------------------
__global__ __launch_bounds__(256, 2) void gemm_bias_relu_kernel(
    const f16* __restrict__ A, const f16* __restrict__ Bt,
    const float* __restrict__ bias, f16* __restrict__ C,
    const float* __restrict__ W3, const float* __restrict__ b3,
    float* __restrict__ out, int K, int head)
{
    extern __shared__ f16 lds[];                 // 3 * 12288 f16 = 72 KiB
    const int tid = threadIdx.x;
    const int wave = tid >> 6, lane = tid & 63;
    const int wm = wave >> 1, wn = wave & 1;
    const int m0 = blockIdx.y * 128;             // y = mblk (slow)
    const int n0 = blockIdx.x * 256;             // x = nblk (fast)

    const int col16 = lane & 15;
    const int quad = lane >> 4;
    const int swz = (quad ^ ((col16 >> 1) & 3)) * 8;   // lane-const slot offset

    f32x4 acc[4][8];
    #pragma unroll
    for (int mi = 0; mi < 4; ++mi)
        #pragma unroll
        for (int ni = 0; ni < 8; ++ni)
            acc[mi][ni] = (f32x4){0.f, 0.f, 0.f, 0.f};

    const size_t strideA = (size_t)MPAD * 32;    // f16 per k-chunk
    const size_t strideB = (size_t)NDIM * 32;
    // A chunk: contiguous 4096 f16; wave w stages segs {w, w+4} (1 KiB each).
    // B chunk: contiguous 8192 f16; wave w stages segs {4w..4w+3}.
    const f16* gA = A + (size_t)m0 * 32 + wave * 512 + lane * 8;
    const f16* gB = Bt + (size_t)n0 * 32 + wave * 2048 + lane * 8;
    const int sAo = wave * 512;                  // + lane*16B implicit
    const int sBo = wave * 2048;

#define STAGE(CN) do { \
        f16* lb_ = lds + ((CN) % 3) * 12288; \
        const f16* ga_ = gA + (size_t)(CN) * strideA; \
        G2L(ga_,        lb_ + sAo); \
        G2L(ga_ + 2048, lb_ + sAo + 2048); \
        const f16* gb_ = gB + (size_t)(CN) * strideB; \
        G2L(gb_,        lb_ + 4096 + sBo); \
        G2L(gb_ + 512,  lb_ + 4096 + sBo + 512); \
        G2L(gb_ + 1024, lb_ + 4096 + sBo + 1024); \
        G2L(gb_ + 1536, lb_ + 4096 + sBo + 1536); \
    } while (0)

    // Prologue: order pinned so the oldest 6 vmem ops are exactly STAGE(0).
    STAGE(0);
    asm volatile("" ::: "memory");
    STAGE(1);
    asm volatile("" ::: "memory");

    const int NC = K >> 5;                       // 32 chunks
    for (int c = 0; c < NC; ++c) {
        if (c + 1 < NC)
            asm volatile("s_waitcnt vmcnt(6)" ::: "memory");
        else
            asm volatile("s_waitcnt vmcnt(0)" ::: "memory");
        __builtin_amdgcn_s_barrier();
        if (c + 2 < NC) STAGE(c + 2);
        asm volatile("" ::: "memory");

        const f16* buf = lds + (c % 3) * 12288;
        const f16* pA = buf + (wm * 64 + col16) * 32 + swz;
        const f16* pB = buf + 4096 + (wn * 128 + col16) * 32 + swz;
        f16x8 af[4], bf[8];
        #pragma unroll
        for (int i = 0; i < 4; ++i)
            af[i] = *(const f16x8*)(pA + i * 512);
        #pragma unroll
        for (int i = 0; i < 8; ++i)
            bf[i] = *(const f16x8*)(pB + i * 512);
        #pragma unroll
        for (int mi = 0; mi < 4; ++mi)
            #pragma unroll
            for (int ni = 0; ni < 8; ++ni)
                acc[mi][ni] = __builtin_amdgcn_mfma_f32_16x16x32_f16(
                    af[mi], bf[ni], acc[mi][ni], 0, 0, 0);
    }
#undef STAGE

    if (!head) {
        #pragma unroll
        for (int ni = 0; ni < 8; ++ni) {
            const int n = n0 + wn * 128 + ni * 16 + col16;
            const float b = bias[n];
            const size_t rb = (size_t)(n >> 5) * MPAD;
            const int noct = (n >> 3) & 3, ne = n & 7;
            #pragma unroll
            for (int mi = 0; mi < 4; ++mi) {
                #pragma unroll
                for (int r = 0; r < 4; ++r) {
                    const int m = m0 + wm * 64 + mi * 16 + quad * 4 + r;
                    float v = fmaxf(acc[mi][ni][r] + b, 0.f);
                    C[(rb + m) * 32 + ((noct ^ ((m >> 1) & 3)) * 8) + ne] = (f16)v;
                }
            }
        }
    } else {
        float bb[8], w3c[8][3];
        #pragma unroll
        for (int ni = 0; ni < 8; ++ni) {
            const int n = n0 + wn * 128 + ni * 16 + col16;
            bb[ni] = bias[n];
            #pragma unroll
            for (int jj = 0; jj < 3; ++jj) w3c[ni][jj] = W3[n * 3 + jj];
        }
        const bool addb3 = (blockIdx.x == 0 && wn == 0);
        #pragma unroll
        for (int mi = 0; mi < 4; ++mi) {
            #pragma unroll
            for (int r = 0; r < 4; ++r) {
                float s0 = 0.f, s1 = 0.f, s2 = 0.f;
                #pragma unroll
                for (int ni = 0; ni < 8; ++ni) {
                    float v = fmaxf(acc[mi][ni][r] + bb[ni], 0.f);
                    s0 += v * w3c[ni][0];
                    s1 += v * w3c[ni][1];
                    s2 += v * w3c[ni][2];
                }
                #pragma unroll
                for (int mask = 1; mask <= 8; mask <<= 1) {
                    s0 += __shfl_xor(s0, mask);
                    s1 += __shfl_xor(s1, mask);
                    s2 += __shfl_xor(s2, mask);
                }
                if (col16 == 0) {
                    const int m = m0 + wm * 64 + mi * 16 + quad * 4 + r;
                    if (m < NLINES) {
                        atomicAdd(&out[m * 3 + 0], s0 + (addb3 ? b3[0] : 0.f));
                        atomicAdd(&out[m * 3 + 1], s1 + (addb3 ? b3[1] : 0.f));
                        atomicAdd(&out[m * 3 + 2], s2 + (addb3 ? b3[2] : 0.f));
                    }
                }
            }
        }
    }
}

// ---------------------------------------------------------------------------
extern "C" void kernel_launch(void* const* d_in, const int* in_sizes, int n_in,
                              void* d_out, int out_size, void* d_ws, size_t ws_size,
                              hipStream_t stream)
{
    const float* jloc = (const float*)d_in[0];
    const float* joff = (const float*)d_in[1];
    const float* loi  = (const float*)d_in[2];
    const int*   eidx = (const int*)d_in[3];
    const float* W1   = (const float*)d_in[4];
    const float* b1   = (const float*)d_in[5];
    const float* W2   = (const float*)d_in[6];
    const float* b2   = (const float*)d_in[7];
    const float* W3   = (const float*)d_in[8];
    const float* b3   = (const float*)d_in[9];
    float* out = (float*)d_out;

    char* ws = (char*)d_ws;
    f16*   loiT  = (f16*)(ws);                            // 4 MB
    f16*   W1T   = (f16*)(ws + ((size_t)4 << 20));        // 2 MB
    f16*   W2T   = (f16*)(ws + ((size_t)6 << 20));        // 2 MB
    float* juncs = (float*)(ws + ((size_t)8 << 20));      // 2.4 KB
    int*   count = (int*)(ws + ((size_t)8 << 20) + 4096);
    unsigned long long* cand =
        (unsigned long long*)(ws + ((size_t)8 << 20) + 8192);  // 32 KB
    f16*   feats = (f16*)(ws + ((size_t)9 << 20));        // 40 MB (tiled MPADx1024)
    f16*   h1    = (f16*)(ws + ((size_t)51 << 20));       // 40 MB (tiled)

    static int attr_done = 0;
    if (!attr_done) {
        (void)hipFuncSetAttribute(
            reinterpret_cast<const void*>(&gemm_bias_relu_kernel),
            hipFuncAttributeMaxDynamicSharedMemorySize, 73728);
        attr_done = 1;
    }

    hipMemsetAsync(count, 0, sizeof(int), stream);
    preproc_kernel<<<dim3(764), dim3(256), 0, stream>>>(
        loi, loiT, W1, W1T, W2, W2T, jloc, cand, count, out, out_size);
    rank_junc_kernel<<<dim3(MAXCAND / 256), dim3(256), 0, stream>>>(
        cand, count, joff, juncs);
    sample_kernel<<<dim3(NLINES / 4), dim3(256), 0, stream>>>(loiT, juncs, eidx, feats);
    gemm_bias_relu_kernel<<<dim3(NDIM / 256, MPAD / 128), dim3(256), 73728, stream>>>(
        feats, W1T, b1, h1, nullptr, nullptr, nullptr, KDIM, 0);
    gemm_bias_relu_kernel<<<dim3(NDIM / 256, MPAD / 128), dim3(256), 73728, stream>>>(
        h1, W2T, b2, nullptr, W3, b3, out, KDIM, 1);
}

// Round 7
// 276.051 us; speedup vs baseline: 1.5426x; 1.0593x over previous
//
#include <hip/hip_runtime.h>
#include <cmath>

// ---------------------------------------------------------------------------
// WireframeDetector: NMS -> top-k 300 junctions -> line sampling (bilinear +
// maxpool) -> 3-layer MLP (fp16 MFMA for the two 1024-wide GEMMs).
// R22: R21 (ring-3 counted-vmcnt, swizzled A/B, 2 blocks/CU -> 76 us) with
//      BM 128->160: grid 628 -> 504 blocks <= 512 = chip residency capacity
//      at 2 blocks/CU -> NO serial third block on any CU. Worst-CU staged
//      volume 2.25 -> 1.66 MB (-26%) at the measured ~30 GB/s/CU delivery
//      -> ~55 us/GEMM predicted. A-chunk is 10 KiB (10 x 1KiB G2L segs,
//      waves 0,1 take 3 segs / waves 2,3 take 2) -> per-wave counted waits
//      vmcnt(7)/vmcnt(6). LDS ring 3 x 26 KiB = 78 KiB (2 blocks = 156 <=
//      160 KiB). acc[5][8] (~230 VGPR, under the 2-block 256 cap; R19's
//      spill tripwire = WRITE_SIZE).
// ---------------------------------------------------------------------------

typedef _Float16 f16;
typedef _Float16 f16x2 __attribute__((ext_vector_type(2)));
typedef _Float16 f16x8 __attribute__((ext_vector_type(8)));
typedef float f32x4 __attribute__((ext_vector_type(4)));

#define HWD 128
#define NPIX 16384            // 128*128
#define TOPK_N 300
#define NLINES 20000
#define MPAD 20160            // 126 * 160 (padded line count)
#define KDIM 1024
#define NDIM 1024
#define MAXCAND 4096

// A operand layout (feats, h1), f16 elems:
//   idx(row,k) = ((k>>5)*MPAD + row)*32 + slot(row,k)*8 + (k&7)
//   slot(row,k) = ((k>>3)&3) ^ ((row>>1)&3)       (XOR bank swizzle)
// B operand layout (W1T, W2T): same with row->n, MPAD->1024:
//   idx(n,k)   = ((k>>5)*1024 + n)*32 + slot(n,k)*8 + (k&7)
// Each 32-k chunk is contiguous (A: 10 KiB per 160 rows, B: 16 KiB per 256
// rows) and IS the LDS image. Fragment ds_read_b128 offset is lane-constant:
// swz = (quad ^ ((col16>>1)&3))*8  (row-block bases are multiples of 16).

// async global->LDS, 16B per lane; LDS dest = wave-uniform base + lane*16
#define G2L(gp, lp) __builtin_amdgcn_global_load_lds( \
    (const __attribute__((address_space(1))) void*)(gp), \
    (__attribute__((address_space(3))) void*)(lp), 16, 0, 0)

// ---------------------------------------------------------------------------
// Fused preprocessing, one dispatch of 764 blocks:
//   blocks 0..127   : transpose loi [C][H][W] fp32 -> loiT [H][W][C] fp16
//   blocks 128..639 : W1/W2 [K][N] fp32 -> swizzled K-chunk-tiled fp16
//   blocks 640..703 : 3x3 NMS on jloc, survivors -> cand list
//   blocks 704..763 : zero out[60000] (consumed by gemm2's atomicAdd epilogue)
// ---------------------------------------------------------------------------
__global__ __launch_bounds__(256) void preproc_kernel(
    const float* __restrict__ loi, f16* __restrict__ loiT,
    const float* __restrict__ W1, f16* __restrict__ W1T,
    const float* __restrict__ W2, f16* __restrict__ W2T,
    const float* __restrict__ jloc, unsigned long long* __restrict__ cand,
    int* __restrict__ count, float* __restrict__ out, int out_n)
{
    const int bid = blockIdx.x;
    const int tid = threadIdx.x;
    if (bid < 128) {
        __shared__ f16 t[128 * 130];     // [x][c], +2 pad kills bank conflicts
        const int y = bid;
        #pragma unroll 4
        for (int it = 0; it < 64; ++it) {
            int idx = it * 256 + tid;    // c-major, x fast -> coalesced read
            int c = idx >> 7, x = idx & 127;
            t[x * 130 + c] = (f16)loi[c * NPIX + y * HWD + x];
        }
        __syncthreads();
        #pragma unroll
        for (int it = 0; it < 8; ++it) {
            int j = it * 256 + tid;      // 2048 chunks of 8 f16
            int x = j >> 4, cc = (j & 15) * 8;
            f16x8 v;
            #pragma unroll
            for (int u = 0; u < 8; ++u) v[u] = t[x * 130 + cc + u];
            *(f16x8*)(loiT + (y * HWD + x) * HWD + cc) = v;
        }
    } else if (bid < 640) {
        const int b = bid - 128;         // 0..511
        const float* W = (b < 256) ? W1 : W2;
        f16* Wt = (b < 256) ? W1T : W2T;
        const int bb = b & 255;
        __shared__ f16 t[64 * 66];
        const int k0 = (bb >> 4) * 64;
        const int n0 = (bb & 15) * 64;
        #pragma unroll 4
        for (int it = 0; it < 16; ++it) {
            int i = it * 256 + tid;      // coalesced read over n
            int r = i >> 6, c = i & 63;
            t[c * 66 + r] = (f16)W[(size_t)(k0 + r) * NDIM + n0 + c];
        }
        __syncthreads();
        #pragma unroll
        for (int it = 0; it < 2; ++it) {
            int j = it * 256 + tid;
            int nr = j >> 3, kc = (j & 7) * 8;
            f16x8 v;
            #pragma unroll
            for (int u = 0; u < 8; ++u) v[u] = t[nr * 66 + kc + u];
            const int kk = k0 + kc;      // multiple of 8
            const int n = n0 + nr;
            const int slot = ((kk >> 3) & 3) ^ ((n >> 1) & 3);
            *(f16x8*)(Wt + ((size_t)(kk >> 5) * NDIM + n) * 32 + slot * 8) = v;
        }
    } else if (bid < 704) {
        const int p = (bid - 640) * 256 + tid;   // 64 blocks x 256 = 16384
        const int y = p >> 7, x = p & 127;
        const float c = jloc[p];
        float m = c;
        for (int dy = -1; dy <= 1; ++dy) {
            int yy = y + dy;
            if (yy < 0 || yy >= HWD) continue;
            for (int dx = -1; dx <= 1; ++dx) {
                int xx = x + dx;
                if (xx < 0 || xx >= HWD) continue;
                m = fmaxf(m, jloc[yy * HWD + xx]);
            }
        }
        if (c == m && c > 0.0f) {
            int pos = atomicAdd(count, 1);
            if (pos < MAXCAND) {
                unsigned int ub = __float_as_uint(c);
                cand[pos] = ((unsigned long long)ub << 32) |
                            (unsigned long long)(0xFFFFFFFFu - (unsigned int)p);
            }
        }
    } else {
        const int base = (bid - 704) * 1024 + tid * 4;   // 60 blocks cover 61440
        #pragma unroll
        for (int u = 0; u < 4; ++u)
            if (base + u < out_n) out[base + u] = 0.f;
    }
}

// ---------------------------------------------------------------------------
// Rank-select top-300, LDS-cached. Keys unique => ranks exact; matches
// jax.lax.top_k order (value desc, index asc).
// ---------------------------------------------------------------------------
__global__ __launch_bounds__(256) void rank_junc_kernel(
    const unsigned long long* __restrict__ cand, const int* __restrict__ count,
    const float* __restrict__ joff, float* __restrict__ juncs /* [300][2] */)
{
    __shared__ unsigned long long keys[MAXCAND];   // 32 KB
    const int n = min(*count, MAXCAND);
    const int t = blockIdx.x * 256 + threadIdx.x;  // 16 blocks = 4096 threads
    for (int i = threadIdx.x; i < n; i += 256)
        keys[i] = cand[i];
    __syncthreads();
    if (t >= n) return;
    const unsigned long long key = keys[t];
    int rank = 0;
    int j = 0;
    for (; j + 4 <= n; j += 4) {
        rank += (keys[j]     > key);
        rank += (keys[j + 1] > key);
        rank += (keys[j + 2] > key);
        rank += (keys[j + 3] > key);
    }
    for (; j < n; ++j) rank += (keys[j] > key);
    if (rank < TOPK_N) {
        unsigned int p = 0xFFFFFFFFu - (unsigned int)(key & 0xFFFFFFFFull);
        // x = idx%w + (sigmoid(joff0)-0.5) + 0.5 = idx%w + sigmoid(joff0)
        float sx = 1.0f / (1.0f + expf(-joff[p]));
        float sy = 1.0f / (1.0f + expf(-joff[NPIX + p]));
        juncs[2 * rank + 0] = (float)(p & 127) + sx;
        juncs[2 * rank + 1] = (float)(p >> 7) + sy;
    }
}

// ---------------------------------------------------------------------------
// Per-line sampling, deduplicated: lanes 0..31 compute the 4 tap offsets +
// weights of the 32 points once into LDS; channel loop (64 lanes, 2 ch each)
// reads them as wave-uniform broadcasts. 4 lines/block (wave per line).
// Output feats in the XOR-swizzled A operand layout.
// ---------------------------------------------------------------------------
__global__ __launch_bounds__(256) void sample_kernel(
    const f16* __restrict__ loiT, const float* __restrict__ juncs,
    const int* __restrict__ edge_idx, f16* __restrict__ feats)
{
    const int wv = threadIdx.x >> 6;
    const int l = blockIdx.x * 4 + wv;
    const int lane = threadIdx.x & 63;

    __shared__ int   soff[4][32][4];   // channel-base element offsets
    __shared__ float swt[4][32][4];    // bilinear weights

    if (lane < 32) {
        const int e0 = edge_idx[2 * l], e1 = edge_idx[2 * l + 1];
        const float ux = juncs[2 * e0], uy = juncs[2 * e0 + 1];
        const float vx = juncs[2 * e1], vy = juncs[2 * e1 + 1];
        const int j = lane;
        const float t = (float)j * (1.0f / 31.0f);
        const float px = ux * t + vx * (1.0f - t) - 0.5f;
        const float py = uy * t + vy * (1.0f - t) - 0.5f;
        float fx0 = fminf(fmaxf(floorf(px), 0.0f), 127.0f);
        float fy0 = fminf(fmaxf(floorf(py), 0.0f), 127.0f);
        float fx1 = fminf(fx0 + 1.0f, 127.0f);
        float fy1 = fminf(fy0 + 1.0f, 127.0f);
        int ix0 = (int)fx0, iy0 = (int)fy0, ix1 = (int)fx1, iy1 = (int)fy1;
        soff[wv][j][0] = (iy0 * HWD + ix0) * HWD;
        soff[wv][j][1] = (iy1 * HWD + ix0) * HWD;
        soff[wv][j][2] = (iy0 * HWD + ix1) * HWD;
        soff[wv][j][3] = (iy1 * HWD + ix1) * HWD;
        swt[wv][j][0] = (fy1 - py) * (fx1 - px);
        swt[wv][j][1] = (py - fy0) * (fx1 - px);
        swt[wv][j][2] = (fy1 - py) * (px - fx0);
        swt[wv][j][3] = (py - fy0) * (px - fx0);
    }
    __syncthreads();

    const int c2 = lane * 2;
    f16x8 o0, o1;
    #pragma unroll
    for (int p = 0; p < 8; ++p) {
        float m0 = -INFINITY, m1 = -INFINITY;
        #pragma unroll
        for (int jj = 0; jj < 4; ++jj) {
            const int j = p * 4 + jj;
            const int b00 = soff[wv][j][0], b10 = soff[wv][j][1];
            const int b01 = soff[wv][j][2], b11 = soff[wv][j][3];
            const float w00 = swt[wv][j][0], w10 = swt[wv][j][1];
            const float w01 = swt[wv][j][2], w11 = swt[wv][j][3];
            f16x2 v00 = *(const f16x2*)(loiT + b00 + c2);
            f16x2 v10 = *(const f16x2*)(loiT + b10 + c2);
            f16x2 v01 = *(const f16x2*)(loiT + b01 + c2);
            f16x2 v11 = *(const f16x2*)(loiT + b11 + c2);
            float s0 = (float)v00.x * w00 + (float)v10.x * w10 +
                       (float)v01.x * w01 + (float)v11.x * w11;
            float s1 = (float)v00.y * w00 + (float)v10.y * w10 +
                       (float)v01.y * w01 + (float)v11.y * w11;
            m0 = fmaxf(m0, s0);
            m1 = fmaxf(m1, s1);
        }
        o0[p] = (f16)m0;   // feature k = 16*lane + p
        o1[p] = (f16)m1;   // feature k = 16*lane + 8 + p
    }
    // A layout: chunk = lane>>1; o0 oct = 2*(lane&1), o1 oct = 2*(lane&1)+1;
    // slot = oct ^ ((l>>1)&3).
    const int rs = (l >> 1) & 3;
    const int oct0 = (lane & 1) * 2;
    f16* base = feats + ((size_t)(lane >> 1) * MPAD + l) * 32;
    *(f16x8*)(base + ((oct0 ^ rs) * 8)) = o0;
    *(f16x8*)(base + (((oct0 + 1) ^ rs) * 8)) = o1;
}

// ---------------------------------------------------------------------------
// GEMM: 160x256 tile, 256 threads, 2x2 waves (each 80 rows x 128 cols,
// acc[5][8]). 32 rounds of one BK=32 chunk. Ring of 3 round-buffers
// (26 KiB each: A 10 KiB + B 16 KiB), prefetch distance 2. Per round:
//   s_waitcnt vmcnt(7|6)  <- per-wave counted (waves 0,1 issue 7 G2L/round,
//                            waves 2,3 issue 6): forces THIS round's buffer
//                            (staged 2 rounds ago); next round's loads stay
//                            in flight. Last round drains vmcnt(0).
//   s_barrier             <- also proves all waves done reading buf (c-1)%3
//   STAGE(c+2)            <- G2L into buffer (c+2)%3 (distinct mod 3)
//   ds_read af[5]/bf[8] (XOR-swizzled, conflict-free) + 40 MFMA
// Grid 504 blocks <= 512 residency capacity -> no serial tail on any CU.
// head=0: C = relu(A@Bt^T + bias), stored in swizzled A layout fp16.
// head=1: v = relu(A@Bt^T + bias); out[m][j] += v . W3  (atomicAdd, + b3 once)
// ---------------------------------------------------------------------------
__global__ __launch_bounds__(256, 2) void gemm_bias_relu_kernel(
    const f16* __restrict__ A, const f16* __restrict__ Bt,
    const float* __restrict__ bias, f16* __restrict__ C,
    const float* __restrict__ W3, const float* __restrict__ b3,
    float* __restrict__ out, int K, int head)
{
    extern __shared__ f16 lds[];                 // 3 * 13312 f16 = 78 KiB
    const int tid = threadIdx.x;
    const int wave = tid >> 6, lane = tid & 63;
    const int wm = wave >> 1, wn = wave & 1;
    const int m0 = blockIdx.y * 160;             // y = mblk (slow)
    const int n0 = blockIdx.x * 256;             // x = nblk (fast)

    const int col16 = lane & 15;
    const int quad = lane >> 4;
    const int swz = (quad ^ ((col16 >> 1) & 3)) * 8;   // lane-const slot offset

    f32x4 acc[5][8];
    #pragma unroll
    for (int mi = 0; mi < 5; ++mi)
        #pragma unroll
        for (int ni = 0; ni < 8; ++ni)
            acc[mi][ni] = (f32x4){0.f, 0.f, 0.f, 0.f};

    const size_t strideA = (size_t)MPAD * 32;    // f16 per k-chunk
    const size_t strideB = (size_t)NDIM * 32;
    // A chunk: contiguous 5120 f16 (10 segs of 1 KiB); wave w stages segs
    // {w, w+4} and (w<2) seg {8+w}. B chunk: 8192 f16; wave w stages 4 segs
    // {4w..4w+3}. lane deposits seg_base + lane*16B. Global == LDS order.
    const f16* gA = A + (size_t)m0 * 32 + wave * 512 + lane * 8;
    const f16* gB = Bt + (size_t)n0 * 32 + wave * 2048 + lane * 8;
    const int sAo = wave * 512;                  // + lane*16B implicit
    const int sBo = wave * 2048;

#define STAGE(CN) do { \
        f16* lb_ = lds + ((CN) % 3) * 13312; \
        const f16* ga_ = gA + (size_t)(CN) * strideA; \
        G2L(ga_,        lb_ + sAo); \
        G2L(ga_ + 2048, lb_ + sAo + 2048); \
        if (wave < 2) G2L(ga_ + 4096, lb_ + sAo + 4096); \
        const f16* gb_ = gB + (size_t)(CN) * strideB; \
        G2L(gb_,        lb_ + 5120 + sBo); \
        G2L(gb_ + 512,  lb_ + 5120 + sBo + 512); \
        G2L(gb_ + 1024, lb_ + 5120 + sBo + 1024); \
        G2L(gb_ + 1536, lb_ + 5120 + sBo + 1536); \
    } while (0)

    // Prologue: order pinned so each wave's oldest G2L batch is STAGE(0).
    STAGE(0);
    asm volatile("" ::: "memory");
    STAGE(1);
    asm volatile("" ::: "memory");

    const int NC = K >> 5;                       // 32 chunks
    for (int c = 0; c < NC; ++c) {
        if (c + 1 < NC) {
            if (wave < 2) asm volatile("s_waitcnt vmcnt(7)" ::: "memory");
            else          asm volatile("s_waitcnt vmcnt(6)" ::: "memory");
        } else {
            asm volatile("s_waitcnt vmcnt(0)" ::: "memory");
        }
        __builtin_amdgcn_s_barrier();
        if (c + 2 < NC) STAGE(c + 2);
        asm volatile("" ::: "memory");

        const f16* buf = lds + (c % 3) * 13312;
        const f16* pA = buf + (wm * 80 + col16) * 32 + swz;
        const f16* pB = buf + 5120 + (wn * 128 + col16) * 32 + swz;
        f16x8 af[5], bf[8];
        #pragma unroll
        for (int i = 0; i < 5; ++i)
            af[i] = *(const f16x8*)(pA + i * 512);
        #pragma unroll
        for (int i = 0; i < 8; ++i)
            bf[i] = *(const f16x8*)(pB + i * 512);
        #pragma unroll
        for (int mi = 0; mi < 5; ++mi)
            #pragma unroll
            for (int ni = 0; ni < 8; ++ni)
                acc[mi][ni] = __builtin_amdgcn_mfma_f32_16x16x32_f16(
                    af[mi], bf[ni], acc[mi][ni], 0, 0, 0);
    }
#undef STAGE

    if (!head) {
        #pragma unroll
        for (int ni = 0; ni < 8; ++ni) {
            const int n = n0 + wn * 128 + ni * 16 + col16;
            const float b = bias[n];
            const size_t rb = (size_t)(n >> 5) * MPAD;
            const int noct = (n >> 3) & 3, ne = n & 7;
            #pragma unroll
            for (int mi = 0; mi < 5; ++mi) {
                #pragma unroll
                for (int r = 0; r < 4; ++r) {
                    const int m = m0 + wm * 80 + mi * 16 + quad * 4 + r;
                    float v = fmaxf(acc[mi][ni][r] + b, 0.f);
                    C[(rb + m) * 32 + ((noct ^ ((m >> 1) & 3)) * 8) + ne] = (f16)v;
                }
            }
        }
    } else {
        float bb[8], w3c[8][3];
        #pragma unroll
        for (int ni = 0; ni < 8; ++ni) {
            const int n = n0 + wn * 128 + ni * 16 + col16;
            bb[ni] = bias[n];
            #pragma unroll
            for (int jj = 0; jj < 3; ++jj) w3c[ni][jj] = W3[n * 3 + jj];
        }
        const bool addb3 = (blockIdx.x == 0 && wn == 0);
        #pragma unroll
        for (int mi = 0; mi < 5; ++mi) {
            #pragma unroll
            for (int r = 0; r < 4; ++r) {
                float s0 = 0.f, s1 = 0.f, s2 = 0.f;
                #pragma unroll
                for (int ni = 0; ni < 8; ++ni) {
                    float v = fmaxf(acc[mi][ni][r] + bb[ni], 0.f);
                    s0 += v * w3c[ni][0];
                    s1 += v * w3c[ni][1];
                    s2 += v * w3c[ni][2];
                }
                #pragma unroll
                for (int mask = 1; mask <= 8; mask <<= 1) {
                    s0 += __shfl_xor(s0, mask);
                    s1 += __shfl_xor(s1, mask);
                    s2 += __shfl_xor(s2, mask);
                }
                if (col16 == 0) {
                    const int m = m0 + wm * 80 + mi * 16 + quad * 4 + r;
                    if (m < NLINES) {
                        atomicAdd(&out[m * 3 + 0], s0 + (addb3 ? b3[0] : 0.f));
                        atomicAdd(&out[m * 3 + 1], s1 + (addb3 ? b3[1] : 0.f));
                        atomicAdd(&out[m * 3 + 2], s2 + (addb3 ? b3[2] : 0.f));
                    }
                }
            }
        }
    }
}

// ---------------------------------------------------------------------------
extern "C" void kernel_launch(void* const* d_in, const int* in_sizes, int n_in,
                              void* d_out, int out_size, void* d_ws, size_t ws_size,
                              hipStream_t stream)
{
    const float* jloc = (const float*)d_in[0];
    const float* joff = (const float*)d_in[1];
    const float* loi  = (const float*)d_in[2];
    const int*   eidx = (const int*)d_in[3];
    const float* W1   = (const float*)d_in[4];
    const float* b1   = (const float*)d_in[5];
    const float* W2   = (const float*)d_in[6];
    const float* b2   = (const float*)d_in[7];
    const float* W3   = (const float*)d_in[8];
    const float* b3   = (const float*)d_in[9];
    float* out = (float*)d_out;

    char* ws = (char*)d_ws;
    f16*   loiT  = (f16*)(ws);                            // 4 MB
    f16*   W1T   = (f16*)(ws + ((size_t)4 << 20));        // 2 MB
    f16*   W2T   = (f16*)(ws + ((size_t)6 << 20));        // 2 MB
    float* juncs = (float*)(ws + ((size_t)8 << 20));      // 2.4 KB
    int*   count = (int*)(ws + ((size_t)8 << 20) + 4096);
    unsigned long long* cand =
        (unsigned long long*)(ws + ((size_t)8 << 20) + 8192);  // 32 KB
    f16*   feats = (f16*)(ws + ((size_t)9 << 20));        // 41.3 MB (tiled MPADx1024)
    f16*   h1    = (f16*)(ws + ((size_t)52 << 20));       // 41.3 MB (tiled)

    static int attr_done = 0;
    if (!attr_done) {
        (void)hipFuncSetAttribute(
            reinterpret_cast<const void*>(&gemm_bias_relu_kernel),
            hipFuncAttributeMaxDynamicSharedMemorySize, 79872);
        attr_done = 1;
    }

    hipMemsetAsync(count, 0, sizeof(int), stream);
    preproc_kernel<<<dim3(764), dim3(256), 0, stream>>>(
        loi, loiT, W1, W1T, W2, W2T, jloc, cand, count, out, out_size);
    rank_junc_kernel<<<dim3(MAXCAND / 256), dim3(256), 0, stream>>>(
        cand, count, joff, juncs);
    sample_kernel<<<dim3(NLINES / 4), dim3(256), 0, stream>>>(loiT, juncs, eidx, feats);
    gemm_bias_relu_kernel<<<dim3(NDIM / 256, MPAD / 160), dim3(256), 79872, stream>>>(
        feats, W1T, b1, h1, nullptr, nullptr, nullptr, KDIM, 0);
    gemm_bias_relu_kernel<<<dim3(NDIM / 256, MPAD / 160), dim3(256), 79872, stream>>>(
        h1, W2T, b2, nullptr, W3, b3, out, KDIM, 1);
}